// Round 4
// baseline (78.291 us; speedup 1.0000x reference)
//
#include <hip/hip_runtime.h>

// TrigoLinear: out[b,o] = sum_i w_out[o,i]*sin(x[b,i]*w_sin[o,i]+b_sin[o,i]) + b_out[o]
// B=2048, I=256, O=512. 268M v_sin ops -> trans-pipe bound.
// Floor: 4096 wave-sins/SIMD * 8cy + 8192 wave-fma * 2cy ~= 49K cy ~= 20.5us.
//
// R4 = R3 structure + R2-validated scalar math (v_pk_fma_f32 inline asm removed
// -- R3's 0.124 absmax implicates its op_sel_hi defaults; packed fp32 saves
// only issue slots, not trans-pipe cycles, so it was zero-gain anyway).
//  - No LDS, no barriers: lane=b, x row lives in VGPRs, 16-i chunks
//    software-pipelined one ahead on vmcnt.
//  - Weights wave-uniform -> s_load streams on scalar pipe (lgkmcnt), fully
//    decoupled from x loads (vmcnt).
//  - prep kernel pre-scales w_sin,b_sin by 1/2pi; v_sin_f32 takes revolutions,
//    |arg| < 0.5 rev so no v_fract needed (validated in R2).

#define B_SZ 2048
#define I_SZ 256
#define O_SZ 512

static constexpr float kInv2Pi = 0.15915494309189535f;

// AC[o][i2] = {ws(2i2), ws(2i2+1), bs(2i2), bs(2i2+1)} * (1/2pi)
// W [o][i2] = {wo(2i2), wo(2i2+1)}
__global__ __launch_bounds__(128) void prep_kernel(
    const float* __restrict__ w, const float* __restrict__ bias,
    float4* __restrict__ AC, float2* __restrict__ W) {
  const int o = blockIdx.x;    // 512
  const int i2 = threadIdx.x;  // 128 pairs of i
  const float4 wq = *reinterpret_cast<const float4*>(&w[o * 2 * I_SZ + 4 * i2]);
  const float b0 = bias[o * (I_SZ + 1) + 2 * i2];
  const float b1 = bias[o * (I_SZ + 1) + 2 * i2 + 1];
  AC[o * 128 + i2] =
      make_float4(wq.y * kInv2Pi, wq.w * kInv2Pi, b0 * kInv2Pi, b1 * kInv2Pi);
  W[o * 128 + i2] = make_float2(wq.x, wq.z);
}

template <bool PREPPED>
__global__ __launch_bounds__(256, 6) void TrigoLinear_kernel(
    const float* __restrict__ x, const float4* __restrict__ AC,
    const float2* __restrict__ W, const float* __restrict__ w_raw,
    const float* __restrict__ bias, float* __restrict__ out) {
  const int tid = threadIdx.x;
  const int lane = tid & 63;
  const int wave = __builtin_amdgcn_readfirstlane(tid >> 6);

  const int btile = blockIdx.x & 31;  // 32 b-tiles
  const int ogrp = blockIdx.x >> 5;   // 64 o-groups of 8
  const int o0 = __builtin_amdgcn_readfirstlane(ogrp * 8 + wave * 2);
  const int o1 = o0 + 1;
  const int b = btile * 64 + lane;

  const float4* __restrict__ xrow =
      reinterpret_cast<const float4*>(x + (size_t)b * I_SZ);  // per-lane row

  // wave-uniform weight stream bases -> scalar loads in the inner loop
  const float4* __restrict__ AC0 = AC + (size_t)o0 * 128;
  const float4* __restrict__ AC1 = AC + (size_t)o1 * 128;
  const float2* __restrict__ W0 = W + (size_t)o0 * 128;
  const float2* __restrict__ W1 = W + (size_t)o1 * 128;
  const float4* __restrict__ WR0 =
      reinterpret_cast<const float4*>(w_raw + (size_t)o0 * 2 * I_SZ);
  const float4* __restrict__ WR1 =
      reinterpret_cast<const float4*>(w_raw + (size_t)o1 * 2 * I_SZ);
  const float* __restrict__ BR0 = bias + (size_t)o0 * (I_SZ + 1);
  const float* __restrict__ BR1 = bias + (size_t)o1 * (I_SZ + 1);

  float acc00 = 0.f, acc01 = 0.f;  // o0: even-i / odd-i partial sums
  float acc10 = 0.f, acc11 = 0.f;  // o1

  // process one 16-i chunk (8 pairs) held in xq[0..3]
  auto process = [&](int c, const float4* xq) {
#pragma unroll
    for (int q = 0; q < 8; ++q) {
      const float4 xv = xq[q >> 1];
      const float xe = (q & 1) ? xv.z : xv.x;  // i = c*16 + 2q
      const float xo = (q & 1) ? xv.w : xv.y;  // i = c*16 + 2q + 1
      const int i2 = c * 8 + q;
      if (PREPPED) {
        const float4 ac0 = AC0[i2];  // {a_e, a_o, c_e, c_o} (pre-scaled)
        const float4 ac1 = AC1[i2];
        const float2 wv0 = W0[i2];   // {wo_e, wo_o}
        const float2 wv1 = W1[i2];
        acc00 = __builtin_fmaf(
            __builtin_amdgcn_sinf(__builtin_fmaf(xe, ac0.x, ac0.z)), wv0.x, acc00);
        acc01 = __builtin_fmaf(
            __builtin_amdgcn_sinf(__builtin_fmaf(xo, ac0.y, ac0.w)), wv0.y, acc01);
        acc10 = __builtin_fmaf(
            __builtin_amdgcn_sinf(__builtin_fmaf(xe, ac1.x, ac1.z)), wv1.x, acc10);
        acc11 = __builtin_fmaf(
            __builtin_amdgcn_sinf(__builtin_fmaf(xo, ac1.y, ac1.w)), wv1.y, acc11);
      } else {
        const float4 wq0 = WR0[i2];  // {wo_e, ws_e, wo_o, ws_o}
        const float4 wq1 = WR1[i2];
        const float be0 = BR0[2 * i2], bo0 = BR0[2 * i2 + 1];
        const float be1 = BR1[2 * i2], bo1 = BR1[2 * i2 + 1];
        float t;
        t = __builtin_fmaf(xe, wq0.y, be0) * kInv2Pi;
        acc00 = __builtin_fmaf(__builtin_amdgcn_sinf(t), wq0.x, acc00);
        t = __builtin_fmaf(xo, wq0.w, bo0) * kInv2Pi;
        acc01 = __builtin_fmaf(__builtin_amdgcn_sinf(t), wq0.z, acc01);
        t = __builtin_fmaf(xe, wq1.y, be1) * kInv2Pi;
        acc10 = __builtin_fmaf(__builtin_amdgcn_sinf(t), wq1.x, acc10);
        t = __builtin_fmaf(xo, wq1.w, bo1) * kInv2Pi;
        acc11 = __builtin_fmaf(__builtin_amdgcn_sinf(t), wq1.z, acc11);
      }
    }
  };

  float4 xq[4], xn[4];
#pragma unroll
  for (int k = 0; k < 4; ++k) xq[k] = xrow[k];

#pragma unroll 1
  for (int c = 0; c < 15; ++c) {
#pragma unroll
    for (int k = 0; k < 4; ++k) xn[k] = xrow[(c + 1) * 4 + k];  // prefetch
    process(c, xq);
#pragma unroll
    for (int k = 0; k < 4; ++k) xq[k] = xn[k];
  }
  process(15, xq);

  out[(size_t)b * O_SZ + o0] = acc00 + acc01 + bias[(size_t)o0 * (I_SZ + 1) + I_SZ];
  out[(size_t)b * O_SZ + o1] = acc10 + acc11 + bias[(size_t)o1 * (I_SZ + 1) + I_SZ];
}

extern "C" void kernel_launch(void* const* d_in, const int* in_sizes, int n_in,
                              void* d_out, int out_size, void* d_ws, size_t ws_size,
                              hipStream_t stream) {
  const float* x = (const float*)d_in[0];     // (2048, 256) f32
  const float* w = (const float*)d_in[1];     // (512, 256, 2) f32
  const float* bias = (const float*)d_in[2];  // (512, 257) f32
  float* out = (float*)d_out;                 // (2048, 512) f32

  const int grid = (B_SZ / 64) * (O_SZ / 8);  // 32 * 64 = 2048 blocks
  const size_t needAC = (size_t)O_SZ * 128 * sizeof(float4);  // 1 MB
  const size_t needW = (size_t)O_SZ * 128 * sizeof(float2);   // 512 KB

  if (ws_size >= needAC + needW) {
    float4* AC = (float4*)d_ws;
    float2* W = (float2*)((char*)d_ws + needAC);
    prep_kernel<<<dim3(O_SZ), dim3(128), 0, stream>>>(w, bias, AC, W);
    TrigoLinear_kernel<true><<<dim3(grid), dim3(256), 0, stream>>>(
        x, AC, W, w, bias, out);
  } else {
    TrigoLinear_kernel<false><<<dim3(grid), dim3(256), 0, stream>>>(
        x, nullptr, nullptr, w, bias, out);
  }
}